// Round 1
// baseline (279.191 us; speedup 1.0000x reference)
//
#include <hip/hip_runtime.h>
#include <math.h>

#define BB 256
#define L 512
#define NSIG 50

__device__ __forceinline__ int refl(int i) {
    if (i < 0) i = -i;
    if (i >= L) i = 2 * L - 2 - i;
    return i;
}

__device__ __forceinline__ float selu(float x) {
    const float scale = 1.0507009873554804934193349852946f;
    const float alpha = 1.6732632423543772848170429916717f;
    return x > 0.f ? scale * x : scale * alpha * (__expf(x) - 1.f);
}

// ---------------- Kernel A: sharedCNN x2 + residual + LayerNorm ----------------
__global__ __launch_bounds__(256) void shared_ln_kernel(
    const float* __restrict__ latent,   // (B, 2048)
    const float* __restrict__ w1, const float* __restrict__ b1,   // (8,4,5),(8,)
    const float* __restrict__ w2, const float* __restrict__ b2,   // (4,8,5),(4,)
    const float* __restrict__ g,  const float* __restrict__ beta, // (512,),(512,)
    float* __restrict__ D)              // (B,4,512)
{
    __shared__ float xb[4][L];
    __shared__ float hb[8][L];
    __shared__ float yb[4][L];
    __shared__ float sw1[160], sb1[8], sw2[160], sb2[4];

    const int b = blockIdx.x;
    const int t = threadIdx.x;

    for (int i = t; i < 160; i += 256) { sw1[i] = w1[i]; sw2[i] = w2[i]; }
    if (t < 8) sb1[t] = b1[t];
    if (t < 4) sb2[t] = b2[t];

    const float* lp = latent + (size_t)b * 2048;
    for (int i = t; i < 2048; i += 256)
        xb[i & 3][i >> 2] = lp[i];   // x[c][l] = latent[l*4+c]
    __syncthreads();

    for (int pass = 0; pass < 2; ++pass) {
        const float (*src)[L] = (pass == 0) ? (const float (*)[L])xb
                                            : (const float (*)[L])yb;
        // conv1: 4->8, k5, d1, pad2, SELU
        for (int idx = t; idx < 8 * L; idx += 256) {
            int co = idx >> 9, l = idx & (L - 1);
            float acc = sb1[co];
            #pragma unroll
            for (int ci = 0; ci < 4; ++ci) {
                const float* w = &sw1[(co * 4 + ci) * 5];
                #pragma unroll
                for (int k = 0; k < 5; ++k)
                    acc += w[k] * src[ci][refl(l + k - 2)];
            }
            hb[co][l] = selu(acc);
        }
        __syncthreads();
        // conv2: 8->4, k5, d2, pad4 (+ residual on pass 1)
        for (int idx = t; idx < 4 * L; idx += 256) {
            int co = idx >> 9, l = idx & (L - 1);
            float acc = sb2[co];
            #pragma unroll
            for (int ci = 0; ci < 8; ++ci) {
                const float* w = &sw2[(co * 8 + ci) * 5];
                #pragma unroll
                for (int k = 0; k < 5; ++k)
                    acc += w[k] * hb[ci][refl(l + 2 * k - 4)];
            }
            if (pass == 1) acc += xb[co][l];
            yb[co][l] = acc;
        }
        __syncthreads();
    }

    // LayerNorm over length axis, one wave per channel (4 waves = 256 threads)
    const int wave = t >> 6;    // channel 0..3
    const int lane = t & 63;
    float v[8];
    float s = 0.f;
    #pragma unroll
    for (int j = 0; j < 8; ++j) { v[j] = yb[wave][lane * 8 + j]; s += v[j]; }
    #pragma unroll
    for (int off = 32; off > 0; off >>= 1) s += __shfl_down(s, off);
    s = __shfl(s, 0);
    const float mu = s * (1.f / 512.f);
    float s2 = 0.f;
    #pragma unroll
    for (int j = 0; j < 8; ++j) { float d = v[j] - mu; s2 += d * d; }
    #pragma unroll
    for (int off = 32; off > 0; off >>= 1) s2 += __shfl_down(s2, off);
    s2 = __shfl(s2, 0);
    const float rinv = rsqrtf(s2 * (1.f / 512.f) + 1e-10f);

    float* Dp = D + ((size_t)b * 4 + wave) * L;
    #pragma unroll
    for (int j = 0; j < 8; ++j) {
        int l = lane * 8 + j;
        Dp[l] = (v[j] - mu) * rinv * g[l] + beta[l];
    }
}

// ---------------- Kernel B: per-signal channel-reduction stack ----------------
__global__ __launch_bounds__(256) void signal_kernel(
    const float* __restrict__ D,   // (B,4,512)
    const float* __restrict__ w1, const float* __restrict__ b1, // (50,8,4,7),(50,8)
    const float* __restrict__ w2, const float* __restrict__ b2, // (50,4,8,5),(50,4)
    const float* __restrict__ w3, const float* __restrict__ b3, // (50,2,4,5),(50,2)
    const float* __restrict__ w4, const float* __restrict__ b4, // (50,1,2,5),(50,1)
    float* __restrict__ out)       // (B,50,512)
{
    const int s = blockIdx.x;
    const int b = blockIdx.y;
    const int t = threadIdx.x;

    __shared__ float db[4][L];
    __shared__ float h1[8][L];
    __shared__ float h2[4][L];
    __shared__ float h3[2][L];
    __shared__ float sw1[224], sw2[160], sw3[40], sw4[10];
    __shared__ float sb1[8], sb2[4], sb3[2], sb4;

    for (int i = t; i < 224; i += 256) sw1[i] = w1[s * 224 + i];
    for (int i = t; i < 160; i += 256) sw2[i] = w2[s * 160 + i];
    if (t < 40) sw3[t] = w3[s * 40 + t];
    if (t < 10) sw4[t] = w4[s * 10 + t];
    if (t < 8)  sb1[t] = b1[s * 8 + t];
    if (t < 4)  sb2[t] = b2[s * 4 + t];
    if (t < 2)  sb3[t] = b3[s * 2 + t];
    if (t == 0) sb4 = b4[s];

    for (int i = t; i < 4 * L; i += 256)
        db[i >> 9][i & (L - 1)] = D[(size_t)b * 4 * L + i];
    __syncthreads();

    // conv1: 4->8, k7, d1, pad3 (no activation)
    for (int idx = t; idx < 8 * L; idx += 256) {
        int co = idx >> 9, l = idx & (L - 1);
        float acc = sb1[co];
        #pragma unroll
        for (int ci = 0; ci < 4; ++ci) {
            const float* w = &sw1[(co * 4 + ci) * 7];
            #pragma unroll
            for (int k = 0; k < 7; ++k)
                acc += w[k] * db[ci][refl(l + k - 3)];
        }
        h1[co][l] = acc;
    }
    __syncthreads();

    // conv2: 8->4, k5, d1, pad2, SELU
    for (int idx = t; idx < 4 * L; idx += 256) {
        int co = idx >> 9, l = idx & (L - 1);
        float acc = sb2[co];
        #pragma unroll
        for (int ci = 0; ci < 8; ++ci) {
            const float* w = &sw2[(co * 8 + ci) * 5];
            #pragma unroll
            for (int k = 0; k < 5; ++k)
                acc += w[k] * h1[ci][refl(l + k - 2)];
        }
        h2[co][l] = selu(acc);
    }
    __syncthreads();

    // conv3: 4->2, k5, d1, pad2 (no activation)
    for (int idx = t; idx < 2 * L; idx += 256) {
        int co = idx >> 9, l = idx & (L - 1);
        float acc = sb3[co];
        #pragma unroll
        for (int ci = 0; ci < 4; ++ci) {
            const float* w = &sw3[(co * 4 + ci) * 5];
            #pragma unroll
            for (int k = 0; k < 5; ++k)
                acc += w[k] * h2[ci][refl(l + k - 2)];
        }
        h3[co][l] = acc;
    }
    __syncthreads();

    // conv4: 2->1, k5, d2, pad4, SELU
    for (int l = t; l < L; l += 256) {
        float acc = sb4;
        #pragma unroll
        for (int ci = 0; ci < 2; ++ci) {
            const float* w = &sw4[ci * 5];
            #pragma unroll
            for (int k = 0; k < 5; ++k)
                acc += w[k] * h3[ci][refl(l + 2 * k - 4)];
        }
        out[((size_t)b * NSIG + s) * L + l] = selu(acc);
    }
}

extern "C" void kernel_launch(void* const* d_in, const int* in_sizes, int n_in,
                              void* d_out, int out_size, void* d_ws, size_t ws_size,
                              hipStream_t stream) {
    const float* latent = (const float*)d_in[0];
    const float* sw1 = (const float*)d_in[1];
    const float* sb1 = (const float*)d_in[2];
    const float* sw2 = (const float*)d_in[3];
    const float* sb2 = (const float*)d_in[4];
    const float* ln_g = (const float*)d_in[5];
    const float* ln_b = (const float*)d_in[6];
    const float* g_w1 = (const float*)d_in[7];
    const float* g_b1 = (const float*)d_in[8];
    const float* g_w2 = (const float*)d_in[9];
    const float* g_b2 = (const float*)d_in[10];
    const float* g_w3 = (const float*)d_in[11];
    const float* g_b3 = (const float*)d_in[12];
    const float* g_w4 = (const float*)d_in[13];
    const float* g_b4 = (const float*)d_in[14];
    float* out = (float*)d_out;
    float* D = (float*)d_ws;   // (256,4,512) f32 = 2 MB

    shared_ln_kernel<<<BB, 256, 0, stream>>>(latent, sw1, sb1, sw2, sb2,
                                             ln_g, ln_b, D);
    signal_kernel<<<dim3(NSIG, BB), 256, 0, stream>>>(D, g_w1, g_b1, g_w2, g_b2,
                                                      g_w3, g_b3, g_w4, g_b4, out);
}

// Round 2
// 105.622 us; speedup vs baseline: 2.6433x; 2.6433x over previous
//
#include <hip/hip_runtime.h>
#include <math.h>

#define BB 256
#define L 512
#define NSIG 50
#define PAD 4
#define STR (L + 2 * PAD)   // 520 floats per padded row

__device__ __forceinline__ int refl(int i) {
    if (i < 0) i = -i;
    if (i >= L) i = 2 * L - 2 - i;
    return i;
}

__device__ __forceinline__ float selu(float x) {
    const float scale = 1.0507009873554804934193349852946f;
    const float alpha = 1.6732632423543772848170429916717f;
    return x > 0.f ? scale * x : scale * alpha * (__expf(x) - 1.f);
}

// ---------------- Kernel A: sharedCNN x2 + residual + LayerNorm ----------------
__global__ __launch_bounds__(256) void shared_ln_kernel(
    const float* __restrict__ latent,   // (B, 2048)
    const float* __restrict__ w1, const float* __restrict__ b1,   // (8,4,5),(8,)
    const float* __restrict__ w2, const float* __restrict__ b2,   // (4,8,5),(4,)
    const float* __restrict__ g,  const float* __restrict__ beta, // (512,),(512,)
    float* __restrict__ D)              // (B,4,512)
{
    __shared__ float xb[4][L];
    __shared__ float hb[8][L];
    __shared__ float yb[4][L];
    __shared__ float sw1[160], sb1[8], sw2[160], sb2[4];

    const int b = blockIdx.x;
    const int t = threadIdx.x;

    for (int i = t; i < 160; i += 256) { sw1[i] = w1[i]; sw2[i] = w2[i]; }
    if (t < 8) sb1[t] = b1[t];
    if (t < 4) sb2[t] = b2[t];

    const float* lp = latent + (size_t)b * 2048;
    for (int i = t; i < 2048; i += 256)
        xb[i & 3][i >> 2] = lp[i];   // x[c][l] = latent[l*4+c]
    __syncthreads();

    for (int pass = 0; pass < 2; ++pass) {
        const float (*src)[L] = (pass == 0) ? (const float (*)[L])xb
                                            : (const float (*)[L])yb;
        // conv1: 4->8, k5, d1, pad2, SELU
        for (int idx = t; idx < 8 * L; idx += 256) {
            int co = idx >> 9, l = idx & (L - 1);
            float acc = sb1[co];
            #pragma unroll
            for (int ci = 0; ci < 4; ++ci) {
                const float* w = &sw1[(co * 4 + ci) * 5];
                #pragma unroll
                for (int k = 0; k < 5; ++k)
                    acc += w[k] * src[ci][refl(l + k - 2)];
            }
            hb[co][l] = selu(acc);
        }
        __syncthreads();
        // conv2: 8->4, k5, d2, pad4 (+ residual on pass 1)
        for (int idx = t; idx < 4 * L; idx += 256) {
            int co = idx >> 9, l = idx & (L - 1);
            float acc = sb2[co];
            #pragma unroll
            for (int ci = 0; ci < 8; ++ci) {
                const float* w = &sw2[(co * 8 + ci) * 5];
                #pragma unroll
                for (int k = 0; k < 5; ++k)
                    acc += w[k] * hb[ci][refl(l + 2 * k - 4)];
            }
            if (pass == 1) acc += xb[co][l];
            yb[co][l] = acc;
        }
        __syncthreads();
    }

    // LayerNorm over length axis, one wave per channel (4 waves = 256 threads)
    const int wave = t >> 6;    // channel 0..3
    const int lane = t & 63;
    float v[8];
    float s = 0.f;
    #pragma unroll
    for (int j = 0; j < 8; ++j) { v[j] = yb[wave][lane * 8 + j]; s += v[j]; }
    #pragma unroll
    for (int off = 32; off > 0; off >>= 1) s += __shfl_down(s, off);
    s = __shfl(s, 0);
    const float mu = s * (1.f / 512.f);
    float s2 = 0.f;
    #pragma unroll
    for (int j = 0; j < 8; ++j) { float d = v[j] - mu; s2 += d * d; }
    #pragma unroll
    for (int off = 32; off > 0; off >>= 1) s2 += __shfl_down(s2, off);
    s2 = __shfl(s2, 0);
    const float rinv = rsqrtf(s2 * (1.f / 512.f) + 1e-10f);

    float* Dp = D + ((size_t)b * 4 + wave) * L;
    #pragma unroll
    for (int j = 0; j < 8; ++j) {
        int l = lane * 8 + j;
        Dp[l] = (v[j] - mu) * rinv * g[l] + beta[l];
    }
}

// ---------------- Kernel B: per-signal channel-reduction stack ----------------
// Register-tiled: each thread owns 2 adjacent positions, computes all output
// channels. Weights read via uniform (blockIdx-based) scalar loads -> SGPRs.
// LDS buffers padded (stride 520) with reflect halo pre-materialized -> no
// refl() in inner loops, linear addressing. Buffer overlay: A = db/h2,
// B = h1/h3.
__global__ __launch_bounds__(256) void signal_kernel(
    const float* __restrict__ D,   // (B,4,512)
    const float* __restrict__ w1, const float* __restrict__ b1, // (50,8,4,7),(50,8)
    const float* __restrict__ w2, const float* __restrict__ b2, // (50,4,8,5),(50,4)
    const float* __restrict__ w3, const float* __restrict__ b3, // (50,2,4,5),(50,2)
    const float* __restrict__ w4, const float* __restrict__ b4, // (50,1,2,5),(50,1)
    float* __restrict__ out)       // (B,50,512)
{
    const int s = blockIdx.x;
    const int b = blockIdx.y;
    const int t = threadIdx.x;
    const int p0 = t * 2;          // this thread's two positions

    __shared__ float bufA[4][STR]; // db, then h2
    __shared__ float bufB[8][STR]; // h1, then h3 (rows 0..1)

    // ---- load D into bufA interior (float4-vectorized, b128 LDS writes) ----
    {
        const float4* Dv = (const float4*)(D + (size_t)b * 4 * L);
        #pragma unroll
        for (int i = t; i < L; i += 256) {       // 512 float4s
            float4 v = Dv[i];
            int c = i >> 7, l4 = (i & 127) * 4;
            float* dst = &bufA[c][PAD + l4];
            dst[0] = v.x; dst[1] = v.y; dst[2] = v.z; dst[3] = v.w;
        }
    }
    __syncthreads();
    // halo fill for bufA rows 0..3
    if (t < 4 * 8) {
        int r = t >> 3, j = t & 7;
        if (j < 4) bufA[r][PAD - 1 - j] = bufA[r][PAD + 1 + j];
        else { int i = j - 4; bufA[r][PAD + L + i] = bufA[r][PAD + L - 2 - i]; }
    }
    __syncthreads();

    // ---- conv1: 4->8, k7, pad3 (no activation). reads bufA, writes bufB ----
    {
        float x[4][8];
        #pragma unroll
        for (int ci = 0; ci < 4; ++ci)
            #pragma unroll
            for (int j = 0; j < 8; ++j)
                x[ci][j] = bufA[ci][p0 + j + (PAD - 3)];
        #pragma unroll
        for (int co = 0; co < 8; ++co) {
            float a0 = b1[s * 8 + co], a1 = a0;
            #pragma unroll
            for (int ci = 0; ci < 4; ++ci)
                #pragma unroll
                for (int k = 0; k < 7; ++k) {
                    float w = w1[((s * 8 + co) * 4 + ci) * 7 + k];
                    a0 += w * x[ci][k];
                    a1 += w * x[ci][k + 1];
                }
            bufB[co][PAD + p0] = a0;
            bufB[co][PAD + p0 + 1] = a1;
        }
    }
    __syncthreads();
    if (t < 8 * 8) {
        int r = t >> 3, j = t & 7;
        if (j < 4) bufB[r][PAD - 1 - j] = bufB[r][PAD + 1 + j];
        else { int i = j - 4; bufB[r][PAD + L + i] = bufB[r][PAD + L - 2 - i]; }
    }
    __syncthreads();

    // ---- conv2: 8->4, k5, pad2, SELU. reads bufB, writes bufA ----
    {
        float x[8][6];
        #pragma unroll
        for (int ci = 0; ci < 8; ++ci)
            #pragma unroll
            for (int j = 0; j < 6; ++j)
                x[ci][j] = bufB[ci][p0 + j + (PAD - 2)];
        #pragma unroll
        for (int co = 0; co < 4; ++co) {
            float a0 = b2[s * 4 + co], a1 = a0;
            #pragma unroll
            for (int ci = 0; ci < 8; ++ci)
                #pragma unroll
                for (int k = 0; k < 5; ++k) {
                    float w = w2[((s * 4 + co) * 8 + ci) * 5 + k];
                    a0 += w * x[ci][k];
                    a1 += w * x[ci][k + 1];
                }
            bufA[co][PAD + p0] = selu(a0);
            bufA[co][PAD + p0 + 1] = selu(a1);
        }
    }
    __syncthreads();
    if (t < 4 * 8) {
        int r = t >> 3, j = t & 7;
        if (j < 4) bufA[r][PAD - 1 - j] = bufA[r][PAD + 1 + j];
        else { int i = j - 4; bufA[r][PAD + L + i] = bufA[r][PAD + L - 2 - i]; }
    }
    __syncthreads();

    // ---- conv3: 4->2, k5, pad2 (no activation). reads bufA, writes bufB ----
    {
        float x[4][6];
        #pragma unroll
        for (int ci = 0; ci < 4; ++ci)
            #pragma unroll
            for (int j = 0; j < 6; ++j)
                x[ci][j] = bufA[ci][p0 + j + (PAD - 2)];
        #pragma unroll
        for (int co = 0; co < 2; ++co) {
            float a0 = b3[s * 2 + co], a1 = a0;
            #pragma unroll
            for (int ci = 0; ci < 4; ++ci)
                #pragma unroll
                for (int k = 0; k < 5; ++k) {
                    float w = w3[((s * 2 + co) * 4 + ci) * 5 + k];
                    a0 += w * x[ci][k];
                    a1 += w * x[ci][k + 1];
                }
            bufB[co][PAD + p0] = a0;
            bufB[co][PAD + p0 + 1] = a1;
        }
    }
    __syncthreads();
    if (t < 2 * 8) {
        int r = t >> 3, j = t & 7;
        if (j < 4) bufB[r][PAD - 1 - j] = bufB[r][PAD + 1 + j];
        else { int i = j - 4; bufB[r][PAD + L + i] = bufB[r][PAD + L - 2 - i]; }
    }
    __syncthreads();

    // ---- conv4: 2->1, k5, d2, pad4, SELU. reads bufB rows 0..1, writes out ----
    {
        float x[2][10];
        #pragma unroll
        for (int ci = 0; ci < 2; ++ci)
            #pragma unroll
            for (int j = 0; j < 10; ++j)
                x[ci][j] = bufB[ci][p0 + j + (PAD - 4)];
        float a0 = b4[s], a1 = a0;
        #pragma unroll
        for (int ci = 0; ci < 2; ++ci)
            #pragma unroll
            for (int k = 0; k < 5; ++k) {
                float w = w4[(s * 2 + ci) * 5 + k];
                a0 += w * x[ci][2 * k];
                a1 += w * x[ci][2 * k + 1];
            }
        float2 r;
        r.x = selu(a0);
        r.y = selu(a1);
        *(float2*)&out[((size_t)b * NSIG + s) * L + p0] = r;
    }
}

extern "C" void kernel_launch(void* const* d_in, const int* in_sizes, int n_in,
                              void* d_out, int out_size, void* d_ws, size_t ws_size,
                              hipStream_t stream) {
    const float* latent = (const float*)d_in[0];
    const float* sw1 = (const float*)d_in[1];
    const float* sb1 = (const float*)d_in[2];
    const float* sw2 = (const float*)d_in[3];
    const float* sb2 = (const float*)d_in[4];
    const float* ln_g = (const float*)d_in[5];
    const float* ln_b = (const float*)d_in[6];
    const float* g_w1 = (const float*)d_in[7];
    const float* g_b1 = (const float*)d_in[8];
    const float* g_w2 = (const float*)d_in[9];
    const float* g_b2 = (const float*)d_in[10];
    const float* g_w3 = (const float*)d_in[11];
    const float* g_b3 = (const float*)d_in[12];
    const float* g_w4 = (const float*)d_in[13];
    const float* g_b4 = (const float*)d_in[14];
    float* out = (float*)d_out;
    float* D = (float*)d_ws;   // (256,4,512) f32 = 2 MB

    shared_ln_kernel<<<BB, 256, 0, stream>>>(latent, sw1, sb1, sw2, sb2,
                                             ln_g, ln_b, D);
    signal_kernel<<<dim3(NSIG, BB), 256, 0, stream>>>(D, g_w1, g_b1, g_w2, g_b2,
                                                      g_w3, g_b3, g_w4, g_b4, out);
}